// Round 9
// baseline (2681.277 us; speedup 1.0000x reference)
//
#include <hip/hip_runtime.h>
#include <math.h>

#define ALPHA_C 0.1f
#define EPB 4096   // edges per block in binning kernels (16 per thread)
#define ESRC 576   // per-wave LDS edge-meta buffer (tile avg 256, +16 self, ~20 sigma)
#define SRCMASK 0x07FFFFFFu

typedef __attribute__((ext_vector_type(4))) float f32x4;
typedef __attribute__((ext_vector_type(8))) short bf16x8;

__device__ __forceinline__ float readlane_f(float v, int l) {
    return __int_as_float(__builtin_amdgcn_readlane(__float_as_int(v), l));
}

__device__ __forceinline__ unsigned short bf16_rtne(float f) {
    unsigned u = __float_as_uint(f);
    unsigned r = (u + 0x7FFFu + ((u >> 16) & 1u)) >> 16;
    return (unsigned short)r;
}

// ---- range histogram: 64 coarse bins ----
__global__ void k_rhist(const int* __restrict__ col, int E, int span,
                        int* __restrict__ rangecount) {
    __shared__ int l[64];
    int tid = threadIdx.x;
    if (tid < 64) l[tid] = 0;
    __syncthreads();
    int base = blockIdx.x * EPB;
#pragma unroll
    for (int it = 0; it < 16; ++it) {
        int e = base + it * 256 + tid;
        if (e < E) atomicAdd(&l[(unsigned)col[e] / (unsigned)span], 1);
    }
    __syncthreads();
    if (tid < 64 && l[tid]) atomicAdd(&rangecount[tid], l[tid]);
}

__global__ void k_rscan(const int* __restrict__ rangecount,
                        int* __restrict__ rangeoffs, int E) {
    __shared__ int s[64];
    int tid = threadIdx.x;
    int v = rangecount[tid];
    s[tid] = v;
    __syncthreads();
    for (int d = 1; d < 64; d <<= 1) {
        int t = (tid >= d) ? s[tid - d] : 0;
        __syncthreads();
        s[tid] += t;
        __syncthreads();
    }
    rangeoffs[tid] = s[tid] - v;
    if (tid == 63) rangeoffs[64] = E;
}

// ---- phase A: bin edges into 64 destination ranges ----
__global__ void k_binA(const int* __restrict__ row, const int* __restrict__ col,
                       const int* __restrict__ rangeoffs, int* __restrict__ gcur,
                       uint2* __restrict__ staged, int E, int span) {
    __shared__ int lrun[64];
    int tid = threadIdx.x;
    int base = blockIdx.x * EPB;
    if (tid < 64) lrun[tid] = 0;
    __syncthreads();
#pragma unroll
    for (int it = 0; it < 16; ++it) {
        int e = base + it * 256 + tid;
        if (e < E) atomicAdd(&lrun[(unsigned)col[e] / (unsigned)span], 1);
    }
    __syncthreads();
    if (tid < 64) {
        int cnt = lrun[tid];
        int gb = cnt ? atomicAdd(&gcur[tid], cnt) : 0;
        lrun[tid] = rangeoffs[tid] + gb;
    }
    __syncthreads();
#pragma unroll
    for (int it = 0; it < 16; ++it) {
        int e = base + it * 256 + tid;
        if (e < E) {
            int c = col[e];
            int r = (unsigned)c / (unsigned)span;
            int pos = atomicAdd(&lrun[r], 1);
            staged[pos] = make_uint2((unsigned)c, (unsigned)row[e]);
        }
    }
}

// ---- phase B: per range: hist -> scan -> offs/dinv -> place (dst-tagged metas) ----
__global__ void k_binB(const uint2* __restrict__ staged, const int* __restrict__ rangeoffs,
                       int* __restrict__ offs, float* __restrict__ dinv,
                       unsigned* __restrict__ srcmeta, int N, int span) {
    __shared__ int lcnt[1600];
    __shared__ int partial[256];
    int r = blockIdx.x;
    int tid = threadIdx.x;
    int nstart = r * span;
    if (nstart >= N) return;
    int nend = nstart + span; if (nend > N) nend = N;
    int cnt = nend - nstart;
    int estart = rangeoffs[r], eend = rangeoffs[r + 1];
    for (int t = tid; t < cnt; t += 256) lcnt[t] = 0;
    __syncthreads();
    for (int e = estart + tid; e < eend; e += 256)
        atomicAdd(&lcnt[(int)staged[e].x - nstart], 1);
    __syncthreads();
    int chunk = (cnt + 255) / 256;
    int c0 = tid * chunk; if (c0 > cnt) c0 = cnt;
    int c1 = c0 + chunk;  if (c1 > cnt) c1 = cnt;
    int sum = 0;
    for (int t = c0; t < c1; ++t) sum += lcnt[t];
    partial[tid] = sum;
    __syncthreads();
    for (int d = 1; d < 256; d <<= 1) {
        int t = (tid >= d) ? partial[tid - d] : 0;
        __syncthreads();
        partial[tid] += t;
        __syncthreads();
    }
    int run = estart + partial[tid] - sum;
    for (int t = c0; t < c1; ++t) {
        int c = lcnt[t];
        lcnt[t] = run;
        offs[nstart + t] = run;
        dinv[nstart + t] = rsqrtf(1.0f + (float)c);
        run += c;
    }
    if (nend == N && tid == 0) offs[N] = eend;
    __syncthreads();
    for (int e = estart + tid; e < eend; e += 256) {
        uint2 cr = staged[e];
        int idx = atomicAdd(&lcnt[(int)cr.x - nstart], 1);
        // meta: src id in low 27 bits, dst tile-row (node & 15) in bits 27-30
        srcmeta[idx] = (cr.y & SRCMASK) | ((cr.x & 15u) << 27);
    }
}

// -- input: h0b = bf16(relu(x @ W_in + b_in));  g = bf16(dinv * relu(...)) --
__global__ void k_in(const float* __restrict__ x, const float* __restrict__ Win,
                     const float* __restrict__ bin, const float* __restrict__ dinv,
                     unsigned short* __restrict__ h0b, unsigned short* __restrict__ g,
                     int N) {
    int lane = threadIdx.x & 63;
    int wave = (blockIdx.x * blockDim.x + threadIdx.x) >> 6;
    int nwaves = (gridDim.x * blockDim.x) >> 6;
    float wreg[17];
#pragma unroll
    for (int k = 0; k < 17; ++k) wreg[k] = Win[k * 64 + lane];
    float breg = bin[lane];
    for (int i = wave; i < N; i += nwaves) {
        float xv = (lane < 17) ? x[i * 17 + lane] : 0.0f;
        float acc = breg;
#pragma unroll
        for (int k = 0; k < 17; ++k) acc += readlane_f(xv, k) * wreg[k];
        float r = fmaxf(acc, 0.0f);
        h0b[(size_t)i * 64 + lane] = bf16_rtne(r);
        g[(size_t)i * 64 + lane] = bf16_rtne(dinv[i] * r);
    }
}

// ---- fused gather+mix: streaming tile gather with ds_add accumulate ----
// per 16-node tile (edges contiguous in CSR): copy dst-tagged metas to LDS,
// append self-edges, stream 64-edge chunks (32 row-loads in flight/wave),
// ds_add_f32 into split-plane atile (lo cols 0-31, hi 32-63, dinv col 67).
//   out = relu( c1*dinv*rawsum + mfma([dinv*rawsum | h0b] @ [bW1 ; bW2+c2*I]) )
template <bool WRITE_G>
__global__ void __launch_bounds__(256, 4)
k_gmix(const unsigned int* __restrict__ gp,
       const unsigned int* __restrict__ h0b,
       const float* __restrict__ W1, const float* __restrict__ W2,
       const float* __restrict__ dinv, const int* __restrict__ offs,
       const unsigned* __restrict__ srcmeta, float beta,
       float* __restrict__ of32, unsigned short* __restrict__ og16,
       int N, int ntiles) {
    __shared__ float atile_s[4][16][68];
    __shared__ unsigned esrc_s[4][ESRC];
    int lane = threadIdx.x & 63;
    int wv = threadIdx.x >> 6;
    float (*atile)[68] = atile_s[wv];     // wave-private
    unsigned* esrc = esrc_s[wv];
    int p = lane & 31, s = lane >> 5;
    int t = (blockIdx.x * blockDim.x + threadIdx.x) >> 6;  // one tile per wave
    if (t >= ntiles) return;
    float c1 = (1.0f - beta) * (1.0f - ALPHA_C);
    float c2 = (1.0f - beta) * ALPHA_C;

    int i0 = t * 16;
    int estart = offs[i0];
    int iend = i0 + 16; if (iend > N) iend = N;
    int eend = offs[iend];

    // ---- zero tile, stash dinv in col 67 ----
    float* af32 = &atile[0][0];
    for (int k = lane; k < 16 * 68; k += 64) af32[k] = 0.0f;
    if (lane < 16) {
        int i = i0 + lane; if (i >= N) i = N - 1;
        atile[lane][67] = dinv[i];
    }

    // ---- streaming gather ----
    int rem = eend - estart;
    int ebase = estart;
    bool self_pending = true;
    while (rem > 0 || self_pending) {
        int nb = rem < (ESRC - 16) ? rem : (ESRC - 16);
        for (int k = lane; k < nb; k += 64) esrc[k] = srcmeta[ebase + k];
        int etot = nb;
        if (nb == rem && self_pending) {   // last batch: append 16 self-edges
            if (lane < 16) {
                int i = i0 + lane; if (i >= N) i = N - 1;
                esrc[nb + lane] = ((unsigned)lane << 27) | (unsigned)i;
            }
            etot += 16;
            self_pending = false;
        }
        ebase += nb; rem -= nb;

        for (int cb = 0; cb < etot; cb += 64) {   // 64 edges, 32 loads in flight
            unsigned meta[32], v[32];
#pragma unroll
            for (int u = 0; u < 32; ++u) {
                int eo = cb + 2 * u + s;
                meta[u] = esrc[eo < etot ? eo : etot - 1];
            }
#pragma unroll
            for (int u = 0; u < 32; ++u)
                v[u] = gp[(size_t)(meta[u] & SRCMASK) * 32 + p];
#pragma unroll
            for (int u = 0; u < 32; ++u) {
                int eo = cb + 2 * u + s;
                if (eo < etot) {
                    int d = (int)(meta[u] >> 27);
                    atomicAdd(&atile[d][p],      __uint_as_float(v[u] << 16));
                    atomicAdd(&atile[d][32 + p], __uint_as_float(v[u] & 0xFFFF0000u));
                }
            }
        }
    }

    // ---- B fragments (built post-gather to cap VGPR pressure) ----
    bf16x8 bfrag[4][4];  // beta*W (+c2*I on the W2 half)
#pragma unroll
    for (int c = 0; c < 4; ++c) {
#pragma unroll
        for (int ks = 0; ks < 4; ++ks) {
            int n = c * 16 + (lane & 15);
            int kb = ks * 32 + (lane >> 4) * 8;
            bf16x8 f;
#pragma unroll
            for (int j = 0; j < 8; ++j) {
                int k = kb + j;
                float w = (k < 64)
                    ? beta * W1[k * 64 + n]
                    : beta * W2[(k - 64) * 64 + n] + (((k - 64) == n) ? c2 : 0.0f);
                f[j] = (short)bf16_rtne(w);
            }
            bfrag[c][ks] = f;
        }
    }

    // ---- MFMA: [dinv*rawsum (LDS) | h0b (global bf16)] @ bfrag ----
    int rl = lane & 15;
    int koff = (lane >> 4) * 8;      // 0,8,16,24
    int grow = i0 + rl; if (grow >= N) grow = N - 1;
    float dvr = atile[rl][67];
    f32x4 acc[4];
#pragma unroll
    for (int c = 0; c < 4; ++c) acc[c] = (f32x4){0.f, 0.f, 0.f, 0.f};
#pragma unroll
    for (int ks = 0; ks < 4; ++ks) {
        bf16x8 af;
        if (ks < 2) {
            int cb2 = ks * 16 + (koff >> 1);    // feats kb..kb+7 -> lo/hi cols cb2..cb2+3
            f32x4 lo4 = *(const f32x4*)&atile[rl][cb2];
            f32x4 hi4 = *(const f32x4*)&atile[rl][32 + cb2];
#pragma unroll
            for (int j = 0; j < 4; ++j) {
                af[2 * j]     = (short)bf16_rtne(dvr * lo4[j]);
                af[2 * j + 1] = (short)bf16_rtne(dvr * hi4[j]);
            }
        } else {
            af = *(const bf16x8*)&h0b[((size_t)grow * 64 + (ks - 2) * 32 + koff) >> 1];
        }
#pragma unroll
        for (int c = 0; c < 4; ++c)
            acc[c] = __builtin_amdgcn_mfma_f32_16x16x32_bf16(af, bfrag[c][ks], acc[c], 0, 0, 0);
    }

    // ---- epilogue: f32 residual + relu, plain stores (R6 pattern) ----
#pragma unroll
    for (int c = 0; c < 4; ++c) {
        int col = c * 16 + rl;
        int lcol = (col & 1) ? (32 + (col >> 1)) : (col >> 1);
#pragma unroll
        for (int q = 0; q < 4; ++q) {
            int row16 = (lane >> 4) * 4 + q;
            int gr = i0 + row16;
            if (gr < N) {
                float dvq = atile[row16][67];
                float v = c1 * dvq * atile[row16][lcol] + acc[c][q];
                float rr = fmaxf(v, 0.0f);
                size_t o = (size_t)gr * 64 + col;
                if (WRITE_G) og16[o] = bf16_rtne(dvq * rr);
                else         of32[o] = rr;
            }
        }
    }
}

// ---------------- head: log_softmax(h @ W_out + b_out) ----------------
__global__ void k_out(const float* __restrict__ h, const float* __restrict__ Wout,
                      const float* __restrict__ bout, float* __restrict__ out, int N) {
    int lane = threadIdx.x & 63;
    int wave = (blockIdx.x * blockDim.x + threadIdx.x) >> 6;
    int nwaves = (gridDim.x * blockDim.x) >> 6;
    float w0 = Wout[lane * 2 + 0], w1 = Wout[lane * 2 + 1];
    float b0 = bout[0], b1 = bout[1];
    for (int i = wave; i < N; i += nwaves) {
        float hv = h[(size_t)i * 64 + lane];
        float p0 = hv * w0, p1 = hv * w1;
#pragma unroll
        for (int d = 32; d > 0; d >>= 1) {
            p0 += __shfl_xor(p0, d, 64);
            p1 += __shfl_xor(p1, d, 64);
        }
        if (lane == 0) {
            float c0 = p0 + b0, c1 = p1 + b1;
            float m = fmaxf(c0, c1);
            float lse = m + logf(expf(c0 - m) + expf(c1 - m));
            out[(size_t)i * 2 + 0] = c0 - lse;
            out[(size_t)i * 2 + 1] = c1 - lse;
        }
    }
}

extern "C" void kernel_launch(void* const* d_in, const int* in_sizes, int n_in,
                              void* d_out, int out_size, void* d_ws, size_t ws_size,
                              hipStream_t stream) {
    const float* x    = (const float*)d_in[0];
    const int*   ei   = (const int*)d_in[1];
    const float* Win  = (const float*)d_in[2];
    const float* bin  = (const float*)d_in[3];
    const float* W1   = (const float*)d_in[4];
    const float* W2   = (const float*)d_in[5];
    const float* Wout = (const float*)d_in[6];
    const float* bout = (const float*)d_in[7];
    float* out = (float*)d_out;

    const int N = in_sizes[0] / 17;
    const int E = in_sizes[1] / 2;
    const int* rowp = ei;
    const int* colp = ei + E;
    const int span = (N + 63) / 64;

    char* p = (char*)d_ws;
    auto alloc = [&](size_t bytes) -> char* {
        char* r = p;
        p += (bytes + 255) & ~(size_t)255;
        return r;
    };
    int*      offs    = (int*)alloc((size_t)(N + 1) * sizeof(int));
    float*    dinv    = (float*)alloc((size_t)N * sizeof(float));
    int*      rc_gc   = (int*)alloc(128 * sizeof(int));
    int*      roffs   = (int*)alloc(65 * sizeof(int));
    unsigned* srcmeta = (unsigned*)alloc((size_t)E * sizeof(unsigned));
    size_t gbytes  = (size_t)N * 64 * sizeof(unsigned short);
    size_t stbytes = (size_t)E * sizeof(uint2);
    char*  stg     = alloc(stbytes > gbytes ? stbytes : gbytes);  // staged, later gB
    unsigned short* h0b  = (unsigned short*)alloc(gbytes);
    float*          hfin = (float*)alloc((size_t)N * 64 * sizeof(float));
    unsigned short* gA   = (unsigned short*)alloc(gbytes);
    uint2*          staged = (uint2*)stg;
    unsigned short* gB     = (unsigned short*)stg;  // staged dead after binB

    int* rangecount = rc_gc;
    int* gcur       = rc_gc + 64;
    hipMemsetAsync(rc_gc, 0, 128 * sizeof(int), stream);

    const int TB = 256;
    const int nbA = (E + EPB - 1) / EPB;

    k_rhist<<<nbA, TB, 0, stream>>>(colp, E, span, rangecount);
    k_rscan<<<1, 64, 0, stream>>>(rangecount, roffs, E);
    k_binA<<<nbA, TB, 0, stream>>>(rowp, colp, roffs, gcur, staged, E, span);
    k_binB<<<64, TB, 0, stream>>>(staged, roffs, offs, dinv, srcmeta, N, span);

    k_in<<<2048, TB, 0, stream>>>(x, Win, bin, dinv, h0b, gA, N);

    const int ntiles = (N + 15) >> 4;
    const int nbG = (ntiles + 3) / 4;   // one tile per wave

    // ping-pong g buffers: L0 gA->gB, L1 gB->gA, L2 gA->gB, L3 gB->hfin(f32)
    for (int l = 0; l < 4; ++l) {
        float beta = logf(0.5f / (float)(l + 1) + 1.0f);
        const unsigned short* gin  = (l & 1) ? gB : gA;
        unsigned short*       gout = (l & 1) ? gA : gB;
        if (l < 3)
            k_gmix<true><<<nbG, TB, 0, stream>>>((const unsigned int*)gin,
                                                 (const unsigned int*)h0b,
                                                 W1 + (size_t)l * 4096, W2 + (size_t)l * 4096,
                                                 dinv, offs, srcmeta, beta,
                                                 nullptr, gout, N, ntiles);
        else
            k_gmix<false><<<nbG, TB, 0, stream>>>((const unsigned int*)gin,
                                                  (const unsigned int*)h0b,
                                                  W1 + (size_t)l * 4096, W2 + (size_t)l * 4096,
                                                  dinv, offs, srcmeta, beta,
                                                  hfin, nullptr, N, ntiles);
    }
    k_out<<<1024, TB, 0, stream>>>(hfin, Wout, bout, out, N);
}

// Round 10
// 462.310 us; speedup vs baseline: 5.7997x; 5.7997x over previous
//
#include <hip/hip_runtime.h>
#include <math.h>

#define ALPHA_C 0.1f
#define EPB 4096  // edges per block in binning kernels (16 per thread)

typedef __attribute__((ext_vector_type(4))) float f32x4;
typedef __attribute__((ext_vector_type(2))) float f32x2;
typedef __attribute__((ext_vector_type(8))) short bf16x8;

__device__ __forceinline__ float readlane_f(float v, int l) {
    return __int_as_float(__builtin_amdgcn_readlane(__float_as_int(v), l));
}

__device__ __forceinline__ unsigned short bf16_rtne(float f) {
    unsigned u = __float_as_uint(f);
    unsigned r = (u + 0x7FFFu + ((u >> 16) & 1u)) >> 16;
    return (unsigned short)r;
}

__device__ __forceinline__ float bflo(unsigned v) { return __uint_as_float(v << 16); }
__device__ __forceinline__ float bfhi(unsigned v) { return __uint_as_float(v & 0xFFFF0000u); }

// ---- range histogram: 64 coarse bins ----
__global__ void k_rhist(const int* __restrict__ col, int E, int span,
                        int* __restrict__ rangecount) {
    __shared__ int l[64];
    int tid = threadIdx.x;
    if (tid < 64) l[tid] = 0;
    __syncthreads();
    int base = blockIdx.x * EPB;
#pragma unroll
    for (int it = 0; it < 16; ++it) {
        int e = base + it * 256 + tid;
        if (e < E) atomicAdd(&l[(unsigned)col[e] / (unsigned)span], 1);
    }
    __syncthreads();
    if (tid < 64 && l[tid]) atomicAdd(&rangecount[tid], l[tid]);
}

__global__ void k_rscan(const int* __restrict__ rangecount,
                        int* __restrict__ rangeoffs, int E) {
    __shared__ int s[64];
    int tid = threadIdx.x;
    int v = rangecount[tid];
    s[tid] = v;
    __syncthreads();
    for (int d = 1; d < 64; d <<= 1) {
        int t = (tid >= d) ? s[tid - d] : 0;
        __syncthreads();
        s[tid] += t;
        __syncthreads();
    }
    rangeoffs[tid] = s[tid] - v;
    if (tid == 63) rangeoffs[64] = E;
}

// ---- phase A: bin edges into 64 destination ranges ----
__global__ void k_binA(const int* __restrict__ row, const int* __restrict__ col,
                       const int* __restrict__ rangeoffs, int* __restrict__ gcur,
                       uint2* __restrict__ staged, int E, int span) {
    __shared__ int lrun[64];
    int tid = threadIdx.x;
    int base = blockIdx.x * EPB;
    if (tid < 64) lrun[tid] = 0;
    __syncthreads();
#pragma unroll
    for (int it = 0; it < 16; ++it) {
        int e = base + it * 256 + tid;
        if (e < E) atomicAdd(&lrun[(unsigned)col[e] / (unsigned)span], 1);
    }
    __syncthreads();
    if (tid < 64) {
        int cnt = lrun[tid];
        int gb = cnt ? atomicAdd(&gcur[tid], cnt) : 0;
        lrun[tid] = rangeoffs[tid] + gb;
    }
    __syncthreads();
#pragma unroll
    for (int it = 0; it < 16; ++it) {
        int e = base + it * 256 + tid;
        if (e < E) {
            int c = col[e];
            int r = (unsigned)c / (unsigned)span;
            int pos = atomicAdd(&lrun[r], 1);
            staged[pos] = make_uint2((unsigned)c, (unsigned)row[e]);
        }
    }
}

// ---- phase B: per range: hist -> scan -> offs/dinv -> place ----
__global__ void k_binB(const uint2* __restrict__ staged, const int* __restrict__ rangeoffs,
                       int* __restrict__ offs, float* __restrict__ dinv,
                       int* __restrict__ srcarr, int N, int span) {
    __shared__ int lcnt[1600];
    __shared__ int partial[256];
    int r = blockIdx.x;
    int tid = threadIdx.x;
    int nstart = r * span;
    if (nstart >= N) return;
    int nend = nstart + span; if (nend > N) nend = N;
    int cnt = nend - nstart;
    int estart = rangeoffs[r], eend = rangeoffs[r + 1];
    for (int t = tid; t < cnt; t += 256) lcnt[t] = 0;
    __syncthreads();
    for (int e = estart + tid; e < eend; e += 256)
        atomicAdd(&lcnt[(int)staged[e].x - nstart], 1);
    __syncthreads();
    int chunk = (cnt + 255) / 256;
    int c0 = tid * chunk; if (c0 > cnt) c0 = cnt;
    int c1 = c0 + chunk;  if (c1 > cnt) c1 = cnt;
    int sum = 0;
    for (int t = c0; t < c1; ++t) sum += lcnt[t];
    partial[tid] = sum;
    __syncthreads();
    for (int d = 1; d < 256; d <<= 1) {
        int t = (tid >= d) ? partial[tid - d] : 0;
        __syncthreads();
        partial[tid] += t;
        __syncthreads();
    }
    int run = estart + partial[tid] - sum;
    for (int t = c0; t < c1; ++t) {
        int c = lcnt[t];
        lcnt[t] = run;
        offs[nstart + t] = run;
        dinv[nstart + t] = rsqrtf(1.0f + (float)c);
        run += c;
    }
    if (nend == N && tid == 0) offs[N] = eend;
    __syncthreads();
    for (int e = estart + tid; e < eend; e += 256) {
        uint2 cr = staged[e];
        int idx = atomicAdd(&lcnt[(int)cr.x - nstart], 1);
        srcarr[idx] = (int)cr.y;
    }
}

// ------- input: h0 = relu(x @ W_in + b_in) (f32);  g = bf16(dinv * h0) -------
__global__ void k_in(const float* __restrict__ x, const float* __restrict__ Win,
                     const float* __restrict__ bin, const float* __restrict__ dinv,
                     float* __restrict__ h0, unsigned short* __restrict__ g, int N) {
    int lane = threadIdx.x & 63;
    int wave = (blockIdx.x * blockDim.x + threadIdx.x) >> 6;
    int nwaves = (gridDim.x * blockDim.x) >> 6;
    float wreg[17];
#pragma unroll
    for (int k = 0; k < 17; ++k) wreg[k] = Win[k * 64 + lane];
    float breg = bin[lane];
    for (int i = wave; i < N; i += nwaves) {
        float xv = (lane < 17) ? x[i * 17 + lane] : 0.0f;
        float acc = breg;
#pragma unroll
        for (int k = 0; k < 17; ++k) acc += readlane_f(xv, k) * wreg[k];
        float r = fmaxf(acc, 0.0f);
        h0[(size_t)i * 64 + lane] = r;
        g[(size_t)i * 64 + lane] = bf16_rtne(dinv[i] * r);
    }
}

// ---- fused gather+mix (R6 structure; gather inner loop = 4-group uint2) ----
//   A[i] = dinv[i]*(sum_e g[src] + g[i])            (gathered into LDS, f32)
//   out  = relu( c1*A + c2*h0 + mfma([A|h0] @ [bW1;bW2]) )
// Gather: group q = lane>>4 (16 lanes, r = lane&15) loads one full 128B row
// per uint2 instruction -> 4 rows/instr, 8-deep unroll = 32 rows in flight.
template <bool WRITE_G>
__global__ void k_gmix(const uint2* __restrict__ gp2, const float* __restrict__ h0,
                       const float* __restrict__ W1, const float* __restrict__ W2,
                       const float* __restrict__ dinv, const int* __restrict__ offs,
                       const int* __restrict__ srcarr, float beta,
                       float* __restrict__ of32, unsigned short* __restrict__ og16,
                       int N, int ntiles) {
    __shared__ float atile_s[4][16][68];
    int lane = threadIdx.x & 63;
    int wv = threadIdx.x >> 6;
    float (*atile)[68] = atile_s[wv];      // wave-private
    int r = lane & 15, q = lane >> 4;      // feature-quad, edge-group
    int wid = (blockIdx.x * blockDim.x + threadIdx.x) >> 6;
    int nw = (gridDim.x * blockDim.x) >> 6;
    float c1 = (1.0f - beta) * (1.0f - ALPHA_C);
    float c2 = (1.0f - beta) * ALPHA_C;

    bf16x8 bfrag[4][4];  // [col-tile][k-step], folded beta*W, resident in VGPRs
#pragma unroll
    for (int c = 0; c < 4; ++c) {
#pragma unroll
        for (int ks = 0; ks < 4; ++ks) {
            int n = c * 16 + (lane & 15);
            int kb = ks * 32 + (lane >> 4) * 8;
            bf16x8 f;
#pragma unroll
            for (int j = 0; j < 8; ++j) {
                int k = kb + j;
                float w = (k < 64) ? beta * W1[k * 64 + n]
                                   : beta * W2[(k - 64) * 64 + n];
                f[j] = (short)bf16_rtne(w);
            }
            bfrag[c][ks] = f;
        }
    }

    for (int t = wid; t < ntiles; t += nw) {
        // ---- gather 16 node rows into LDS tile ----
        for (int ii = 0; ii < 16; ++ii) {
            int i = t * 16 + ii; if (i >= N) i = N - 1;
            int e0 = offs[i], e1 = offs[i + 1];
            float a0 = 0.0f, a1 = 0.0f, a2 = 0.0f, a3 = 0.0f;
            for (int base = e0; base < e1; base += 32) {   // 32 edges, 8 per group
                int idx[8];
                uint2 v[8];
#pragma unroll
                for (int u = 0; u < 8; ++u) {
                    int eo = base + u * 4 + q;
                    idx[u] = srcarr[eo < e1 ? eo : e1 - 1];
                }
#pragma unroll
                for (int u = 0; u < 8; ++u) v[u] = gp2[(size_t)idx[u] * 16 + r];
#pragma unroll
                for (int u = 0; u < 8; ++u) {
                    bool ok = (base + u * 4 + q) < e1;
                    a0 += ok ? bflo(v[u].x) : 0.0f;
                    a1 += ok ? bfhi(v[u].x) : 0.0f;
                    a2 += ok ? bflo(v[u].y) : 0.0f;
                    a3 += ok ? bfhi(v[u].y) : 0.0f;
                }
            }
            // combine the 4 groups (lanes with equal r hold the same feats)
            a0 += __shfl_xor(a0, 16, 64); a0 += __shfl_xor(a0, 32, 64);
            a1 += __shfl_xor(a1, 16, 64); a1 += __shfl_xor(a1, 32, 64);
            a2 += __shfl_xor(a2, 16, 64); a2 += __shfl_xor(a2, 32, 64);
            a3 += __shfl_xor(a3, 16, 64); a3 += __shfl_xor(a3, 32, 64);
            if (q == 0) {
                uint2 sv = gp2[(size_t)i * 16 + r];  // self-loop term
                float di = dinv[i];
                f32x4 w = {di * (a0 + bflo(sv.x)), di * (a1 + bfhi(sv.x)),
                           di * (a2 + bflo(sv.y)), di * (a3 + bfhi(sv.y))};
                *(f32x4*)&atile[ii][4 * r] = w;
                if (r == 0) atile[ii][66] = di;      // stash dinv for epilogue
            }
        }

        // ---- MFMA: [A(LDS f32) | h0(global f32)] @ bfrag ----
        int rl = lane & 15;
        int koff = (lane >> 4) * 8;
        int grow = t * 16 + rl; if (grow >= N) grow = N - 1;
        f32x4 acc[4];
#pragma unroll
        for (int c = 0; c < 4; ++c) acc[c] = (f32x4){0.f, 0.f, 0.f, 0.f};
#pragma unroll
        for (int ks = 0; ks < 4; ++ks) {
            const float* sp = (ks < 2)
                ? &atile[rl][ks * 32 + koff]
                : &h0[(size_t)grow * 64 + (ks - 2) * 32 + koff];
            f32x4 lo = *(const f32x4*)sp;
            f32x4 hi = *(const f32x4*)(sp + 4);
            bf16x8 af;
#pragma unroll
            for (int j = 0; j < 4; ++j) af[j] = (short)bf16_rtne(lo[j]);
#pragma unroll
            for (int j = 0; j < 4; ++j) af[4 + j] = (short)bf16_rtne(hi[j]);
#pragma unroll
            for (int c = 0; c < 4; ++c)
                acc[c] = __builtin_amdgcn_mfma_f32_16x16x32_bf16(af, bfrag[c][ks], acc[c], 0, 0, 0);
        }

        // ---- epilogue: f32 residual + relu ----
#pragma unroll
        for (int c = 0; c < 4; ++c) {
            int col = c * 16 + rl;
#pragma unroll
            for (int qq = 0; qq < 4; ++qq) {
                int row16 = (lane >> 4) * 4 + qq;
                int gr = t * 16 + row16;
                if (gr < N) {
                    size_t o = (size_t)gr * 64 + col;
                    float v = c1 * atile[row16][col] + c2 * h0[o] + acc[c][qq];
                    float rr = fmaxf(v, 0.0f);
                    if (WRITE_G) og16[o] = bf16_rtne(atile[row16][66] * rr);
                    else         of32[o] = rr;
                }
            }
        }
    }
}

// ---------------- head: log_softmax(h @ W_out + b_out) ----------------
__global__ void k_out(const float* __restrict__ h, const float* __restrict__ Wout,
                      const float* __restrict__ bout, float* __restrict__ out, int N) {
    int lane = threadIdx.x & 63;
    int wave = (blockIdx.x * blockDim.x + threadIdx.x) >> 6;
    int nwaves = (gridDim.x * blockDim.x) >> 6;
    float w0 = Wout[lane * 2 + 0], w1 = Wout[lane * 2 + 1];
    float b0 = bout[0], b1 = bout[1];
    for (int i = wave; i < N; i += nwaves) {
        float hv = h[(size_t)i * 64 + lane];
        float p0 = hv * w0, p1 = hv * w1;
#pragma unroll
        for (int d = 32; d > 0; d >>= 1) {
            p0 += __shfl_xor(p0, d, 64);
            p1 += __shfl_xor(p1, d, 64);
        }
        if (lane == 0) {
            float c0 = p0 + b0, c1 = p1 + b1;
            float m = fmaxf(c0, c1);
            float lse = m + logf(expf(c0 - m) + expf(c1 - m));
            out[(size_t)i * 2 + 0] = c0 - lse;
            out[(size_t)i * 2 + 1] = c1 - lse;
        }
    }
}

extern "C" void kernel_launch(void* const* d_in, const int* in_sizes, int n_in,
                              void* d_out, int out_size, void* d_ws, size_t ws_size,
                              hipStream_t stream) {
    const float* x    = (const float*)d_in[0];
    const int*   ei   = (const int*)d_in[1];
    const float* Win  = (const float*)d_in[2];
    const float* bin  = (const float*)d_in[3];
    const float* W1   = (const float*)d_in[4];
    const float* W2   = (const float*)d_in[5];
    const float* Wout = (const float*)d_in[6];
    const float* bout = (const float*)d_in[7];
    float* out = (float*)d_out;

    const int N = in_sizes[0] / 17;
    const int E = in_sizes[1] / 2;
    const int* rowp = ei;
    const int* colp = ei + E;
    const int span = (N + 63) / 64;   // <= 1600 assumed

    char* p = (char*)d_ws;
    auto alloc = [&](size_t bytes) -> char* {
        char* r = p;
        p += (bytes + 255) & ~(size_t)255;
        return r;
    };
    int*   offs   = (int*)alloc((size_t)(N + 1) * sizeof(int));
    float* dinv   = (float*)alloc((size_t)N * sizeof(float));
    int*   rc_gc  = (int*)alloc(128 * sizeof(int));
    int*   roffs  = (int*)alloc(65 * sizeof(int));
    int*   srcarr = (int*)alloc((size_t)E * sizeof(int));
    size_t gbytes  = (size_t)N * 64 * sizeof(unsigned short);
    size_t stbytes = (size_t)E * sizeof(uint2);
    char*  stg    = alloc(stbytes > gbytes ? stbytes : gbytes);  // staged, later gB
    float*          h0   = (float*)alloc((size_t)N * 64 * sizeof(float));
    float*          hfin = (float*)alloc((size_t)N * 64 * sizeof(float));
    unsigned short* gA   = (unsigned short*)alloc(gbytes);
    uint2*          staged = (uint2*)stg;
    unsigned short* gB     = (unsigned short*)stg;  // staged dead after binB

    int* rangecount = rc_gc;
    int* gcur       = rc_gc + 64;
    hipMemsetAsync(rc_gc, 0, 128 * sizeof(int), stream);

    const int TB = 256;
    const int nbA = (E + EPB - 1) / EPB;

    k_rhist<<<nbA, TB, 0, stream>>>(colp, E, span, rangecount);
    k_rscan<<<1, 64, 0, stream>>>(rangecount, roffs, E);
    k_binA<<<nbA, TB, 0, stream>>>(rowp, colp, roffs, gcur, staged, E, span);
    k_binB<<<64, TB, 0, stream>>>(staged, roffs, offs, dinv, srcarr, N, span);

    k_in<<<2048, TB, 0, stream>>>(x, Win, bin, dinv, h0, gA, N);

    const int ntiles = (N + 15) >> 4;

    // ping-pong g buffers: L0 gA->gB, L1 gB->gA, L2 gA->gB, L3 gB->hfin(f32)
    for (int l = 0; l < 4; ++l) {
        float beta = logf(0.5f / (float)(l + 1) + 1.0f);
        const unsigned short* gin  = (l & 1) ? gB : gA;
        unsigned short*       gout = (l & 1) ? gA : gB;
        if (l < 3)
            k_gmix<true><<<1024, TB, 0, stream>>>((const uint2*)gin, h0,
                                                  W1 + (size_t)l * 4096, W2 + (size_t)l * 4096,
                                                  dinv, offs, srcarr, beta,
                                                  nullptr, gout, N, ntiles);
        else
            k_gmix<false><<<1024, TB, 0, stream>>>((const uint2*)gin, h0,
                                                   W1 + (size_t)l * 4096, W2 + (size_t)l * 4096,
                                                   dinv, offs, srcarr, beta,
                                                   hfin, nullptr, N, ntiles);
    }
    k_out<<<1024, TB, 0, stream>>>(hfin, Wout, bout, out, N);
}

// Round 11
// 445.504 us; speedup vs baseline: 6.0185x; 1.0377x over previous
//
#include <hip/hip_runtime.h>
#include <math.h>

#define ALPHA_C 0.1f
#define EPB 4096  // edges per block in binning kernels (16 per thread)

typedef __attribute__((ext_vector_type(4))) float f32x4;
typedef __attribute__((ext_vector_type(8))) short bf16x8;

__device__ __forceinline__ float readlane_f(float v, int l) {
    return __int_as_float(__builtin_amdgcn_readlane(__float_as_int(v), l));
}

__device__ __forceinline__ unsigned short bf16_rtne(float f) {
    unsigned u = __float_as_uint(f);
    unsigned r = (u + 0x7FFFu + ((u >> 16) & 1u)) >> 16;
    return (unsigned short)r;
}

__device__ __forceinline__ float bflo(unsigned v) { return __uint_as_float(v << 16); }
__device__ __forceinline__ float bfhi(unsigned v) { return __uint_as_float(v & 0xFFFF0000u); }

// ---- range histogram: 64 coarse bins ----
__global__ void k_rhist(const int* __restrict__ col, int E, int span,
                        int* __restrict__ rangecount) {
    __shared__ int l[64];
    int tid = threadIdx.x;
    if (tid < 64) l[tid] = 0;
    __syncthreads();
    int base = blockIdx.x * EPB;
#pragma unroll
    for (int it = 0; it < 16; ++it) {
        int e = base + it * 256 + tid;
        if (e < E) atomicAdd(&l[(unsigned)col[e] / (unsigned)span], 1);
    }
    __syncthreads();
    if (tid < 64 && l[tid]) atomicAdd(&rangecount[tid], l[tid]);
}

__global__ void k_rscan(const int* __restrict__ rangecount,
                        int* __restrict__ rangeoffs, int E) {
    __shared__ int s[64];
    int tid = threadIdx.x;
    int v = rangecount[tid];
    s[tid] = v;
    __syncthreads();
    for (int d = 1; d < 64; d <<= 1) {
        int t = (tid >= d) ? s[tid - d] : 0;
        __syncthreads();
        s[tid] += t;
        __syncthreads();
    }
    rangeoffs[tid] = s[tid] - v;
    if (tid == 63) rangeoffs[64] = E;
}

// ---- phase A: bin edges into 64 destination ranges (packed 4B metas) ----
// meta = (src << 11) | (dst - range_start)   [src<=2^17, local dst < 2048]
__global__ void k_binA(const int* __restrict__ row, const int* __restrict__ col,
                       const int* __restrict__ rangeoffs, int* __restrict__ gcur,
                       unsigned* __restrict__ staged, int E, int span) {
    __shared__ int lrun[64];
    int tid = threadIdx.x;
    int base = blockIdx.x * EPB;
    if (tid < 64) lrun[tid] = 0;
    __syncthreads();
#pragma unroll
    for (int it = 0; it < 16; ++it) {
        int e = base + it * 256 + tid;
        if (e < E) atomicAdd(&lrun[(unsigned)col[e] / (unsigned)span], 1);
    }
    __syncthreads();
    if (tid < 64) {
        int cnt = lrun[tid];
        int gb = cnt ? atomicAdd(&gcur[tid], cnt) : 0;
        lrun[tid] = rangeoffs[tid] + gb;
    }
    __syncthreads();
#pragma unroll
    for (int it = 0; it < 16; ++it) {
        int e = base + it * 256 + tid;
        if (e < E) {
            int c = col[e];
            int r = (unsigned)c / (unsigned)span;
            int pos = atomicAdd(&lrun[r], 1);
            staged[pos] = ((unsigned)row[e] << 11) | (unsigned)(c - r * span);
        }
    }
}

// ---- phase B: per range: hist -> scan -> offs/dinv -> place ----
__global__ void k_binB(const unsigned* __restrict__ staged, const int* __restrict__ rangeoffs,
                       int* __restrict__ offs, float* __restrict__ dinv,
                       int* __restrict__ srcarr, int N, int span) {
    __shared__ int lcnt[1600];
    __shared__ int partial[256];
    int r = blockIdx.x;
    int tid = threadIdx.x;
    int nstart = r * span;
    if (nstart >= N) return;
    int nend = nstart + span; if (nend > N) nend = N;
    int cnt = nend - nstart;
    int estart = rangeoffs[r], eend = rangeoffs[r + 1];
    for (int t = tid; t < cnt; t += 256) lcnt[t] = 0;
    __syncthreads();
    for (int e = estart + tid; e < eend; e += 256)
        atomicAdd(&lcnt[staged[e] & 0x7FFu], 1);
    __syncthreads();
    int chunk = (cnt + 255) / 256;
    int c0 = tid * chunk; if (c0 > cnt) c0 = cnt;
    int c1 = c0 + chunk;  if (c1 > cnt) c1 = cnt;
    int sum = 0;
    for (int t = c0; t < c1; ++t) sum += lcnt[t];
    partial[tid] = sum;
    __syncthreads();
    for (int d = 1; d < 256; d <<= 1) {
        int t = (tid >= d) ? partial[tid - d] : 0;
        __syncthreads();
        partial[tid] += t;
        __syncthreads();
    }
    int run = estart + partial[tid] - sum;
    for (int t = c0; t < c1; ++t) {
        int c = lcnt[t];
        lcnt[t] = run;
        offs[nstart + t] = run;
        dinv[nstart + t] = rsqrtf(1.0f + (float)c);
        run += c;
    }
    if (nend == N && tid == 0) offs[N] = eend;
    __syncthreads();
    for (int e = estart + tid; e < eend; e += 256) {
        unsigned m = staged[e];
        int idx = atomicAdd(&lcnt[m & 0x7FFu], 1);
        srcarr[idx] = (int)(m >> 11);
    }
}

// ---- fold weights: wf[n][k] = bf16( k<64 ? b*W1[k][n] : b*W2[k-64][n] + (k-64==n)*c2 ) ----
__global__ void k_wfold(const float* __restrict__ W1, const float* __restrict__ W2,
                        float beta, float c2, unsigned short* __restrict__ wf) {
    int idx = blockIdx.x * 256 + threadIdx.x;
    if (idx < 8192) {
        int n = idx >> 7, k = idx & 127;
        float w = (k < 64) ? beta * W1[k * 64 + n]
                           : beta * W2[(k - 64) * 64 + n] + (((k - 64) == n) ? c2 : 0.0f);
        wf[idx] = bf16_rtne(w);
    }
}

// -- input: h0b = bf16(relu(x @ W_in + b_in));  g = bf16(dinv * relu(...)) --
__global__ void k_in(const float* __restrict__ x, const float* __restrict__ Win,
                     const float* __restrict__ bin, const float* __restrict__ dinv,
                     unsigned short* __restrict__ h0b, unsigned short* __restrict__ g,
                     int N) {
    int lane = threadIdx.x & 63;
    int wave = (blockIdx.x * blockDim.x + threadIdx.x) >> 6;
    int nwaves = (gridDim.x * blockDim.x) >> 6;
    float wreg[17];
#pragma unroll
    for (int k = 0; k < 17; ++k) wreg[k] = Win[k * 64 + lane];
    float breg = bin[lane];
    for (int i = wave; i < N; i += nwaves) {
        float xv = (lane < 17) ? x[i * 17 + lane] : 0.0f;
        float acc = breg;
#pragma unroll
        for (int k = 0; k < 17; ++k) acc += readlane_f(xv, k) * wreg[k];
        float r = fmaxf(acc, 0.0f);
        h0b[(size_t)i * 64 + lane] = bf16_rtne(r);
        g[(size_t)i * 64 + lane] = bf16_rtne(dinv[i] * r);
    }
}

// ---- fused gather+mix (R10 gather loop, untouched) ----
//   A[i] = dinv[i]*(sum_e g[src] + g[i])            (gathered into LDS, f32)
//   h    = relu( c1*A + mfma([A | h0b] @ wf) )      (c2*I folded into wf)
// MODE 0: write g' = bf16(dinv*h) to og16 (ping-pong buffer)
// MODE 1: last layer -> fused head: out = log_softmax(h @ Wout + bout)
template <int MODE>
__global__ void k_gmix(const uint2* __restrict__ gp2,
                       const unsigned short* __restrict__ h0b,
                       const unsigned short* __restrict__ wf,
                       const float* __restrict__ dinv, const int* __restrict__ offs,
                       const int* __restrict__ srcarr, float c1,
                       const float* __restrict__ Wout, const float* __restrict__ bout,
                       float* __restrict__ out, unsigned short* __restrict__ og16,
                       int N, int ntiles) {
    __shared__ float atile_s[4][16][68];
    int lane = threadIdx.x & 63;
    int wv = threadIdx.x >> 6;
    float (*atile)[68] = atile_s[wv];      // wave-private
    int r = lane & 15, q = lane >> 4;      // feature-quad, edge-group
    int t = (blockIdx.x * blockDim.x + threadIdx.x) >> 6;  // one tile per wave
    if (t >= ntiles) return;

    // B fragments from the pre-folded table: 16 vector loads, no converts
    int rl = lane & 15;
    int koff = (lane >> 4) * 8;
    bf16x8 bfrag[4][4];
#pragma unroll
    for (int c = 0; c < 4; ++c)
#pragma unroll
        for (int ks = 0; ks < 4; ++ks)
            bfrag[c][ks] = *(const bf16x8*)&wf[(c * 16 + rl) * 128 + ks * 32 + koff];

    // ---- gather 16 node rows into LDS tile (R10 inner loop) ----
    for (int ii = 0; ii < 16; ++ii) {
        int i = t * 16 + ii; if (i >= N) i = N - 1;
        int e0 = offs[i], e1 = offs[i + 1];
        float a0 = 0.0f, a1 = 0.0f, a2 = 0.0f, a3 = 0.0f;
        for (int base = e0; base < e1; base += 32) {   // 32 edges, 8 per group
            int idx[8];
            uint2 v[8];
#pragma unroll
            for (int u = 0; u < 8; ++u) {
                int eo = base + u * 4 + q;
                idx[u] = srcarr[eo < e1 ? eo : e1 - 1];
            }
#pragma unroll
            for (int u = 0; u < 8; ++u) v[u] = gp2[(size_t)idx[u] * 16 + r];
#pragma unroll
            for (int u = 0; u < 8; ++u) {
                bool ok = (base + u * 4 + q) < e1;
                a0 += ok ? bflo(v[u].x) : 0.0f;
                a1 += ok ? bfhi(v[u].x) : 0.0f;
                a2 += ok ? bflo(v[u].y) : 0.0f;
                a3 += ok ? bfhi(v[u].y) : 0.0f;
            }
        }
        a0 += __shfl_xor(a0, 16, 64); a0 += __shfl_xor(a0, 32, 64);
        a1 += __shfl_xor(a1, 16, 64); a1 += __shfl_xor(a1, 32, 64);
        a2 += __shfl_xor(a2, 16, 64); a2 += __shfl_xor(a2, 32, 64);
        a3 += __shfl_xor(a3, 16, 64); a3 += __shfl_xor(a3, 32, 64);
        if (q == 0) {
            uint2 sv = gp2[(size_t)i * 16 + r];  // self-loop term
            float di = dinv[i];
            f32x4 w = {di * (a0 + bflo(sv.x)), di * (a1 + bfhi(sv.x)),
                       di * (a2 + bflo(sv.y)), di * (a3 + bfhi(sv.y))};
            *(f32x4*)&atile[ii][4 * r] = w;
            if (r == 0) atile[ii][66] = di;      // dinv for MODE 0 epilogue
        }
    }

    // ---- MFMA: [A(LDS f32) | h0b(bf16)] @ bfrag ----
    int grow = t * 16 + rl; if (grow >= N) grow = N - 1;
    f32x4 acc[4];
#pragma unroll
    for (int c = 0; c < 4; ++c) acc[c] = (f32x4){0.f, 0.f, 0.f, 0.f};
#pragma unroll
    for (int ks = 0; ks < 4; ++ks) {
        bf16x8 af;
        if (ks < 2) {
            const float* sp = &atile[rl][ks * 32 + koff];
            f32x4 lo = *(const f32x4*)sp;
            f32x4 hi = *(const f32x4*)(sp + 4);
#pragma unroll
            for (int j = 0; j < 4; ++j) af[j] = (short)bf16_rtne(lo[j]);
#pragma unroll
            for (int j = 0; j < 4; ++j) af[4 + j] = (short)bf16_rtne(hi[j]);
        } else {
            af = *(const bf16x8*)&h0b[(size_t)grow * 64 + (ks - 2) * 32 + koff];
        }
#pragma unroll
        for (int c = 0; c < 4; ++c)
            acc[c] = __builtin_amdgcn_mfma_f32_16x16x32_bf16(af, bfrag[c][ks], acc[c], 0, 0, 0);
    }

    if (MODE == 0) {
        // ---- epilogue: h = relu(c1*A + acc); write g' = bf16(dinv*h) ----
#pragma unroll
        for (int c = 0; c < 4; ++c) {
            int col = c * 16 + rl;
#pragma unroll
            for (int qq = 0; qq < 4; ++qq) {
                int row16 = (lane >> 4) * 4 + qq;
                int gr = t * 16 + row16;
                if (gr < N) {
                    float v = c1 * atile[row16][col] + acc[c][qq];
                    float rr = fmaxf(v, 0.0f);
                    og16[(size_t)gr * 64 + col] = bf16_rtne(atile[row16][66] * rr);
                }
            }
        }
    } else {
        // ---- fused head: logits = h @ Wout + bout; out = log_softmax ----
        float w0c[4], w1c[4];
#pragma unroll
        for (int c = 0; c < 4; ++c) {
            int col = c * 16 + rl;
            w0c[c] = Wout[col * 2 + 0];
            w1c[c] = Wout[col * 2 + 1];
        }
        float b0 = bout[0], b1 = bout[1];
        float hq[4][4];
#pragma unroll
        for (int c = 0; c < 4; ++c) {
            int col = c * 16 + rl;
#pragma unroll
            for (int qq = 0; qq < 4; ++qq) {
                int row16 = (lane >> 4) * 4 + qq;
                hq[c][qq] = fmaxf(c1 * atile[row16][col] + acc[c][qq], 0.0f);
            }
        }
#pragma unroll
        for (int qq = 0; qq < 4; ++qq) {
            float p0 = hq[0][qq] * w0c[0] + hq[1][qq] * w0c[1]
                     + hq[2][qq] * w0c[2] + hq[3][qq] * w0c[3];
            float p1 = hq[0][qq] * w1c[0] + hq[1][qq] * w1c[1]
                     + hq[2][qq] * w1c[2] + hq[3][qq] * w1c[3];
#pragma unroll
            for (int d = 1; d < 16; d <<= 1) {   // reduce across the 16-lane group
                p0 += __shfl_xor(p0, d, 64);
                p1 += __shfl_xor(p1, d, 64);
            }
            int row16 = (lane >> 4) * 4 + qq;
            int gr = t * 16 + row16;
            if (rl == 0 && gr < N) {
                float l0 = p0 + b0, l1 = p1 + b1;
                float m = fmaxf(l0, l1);
                float lse = m + logf(expf(l0 - m) + expf(l1 - m));
                out[(size_t)gr * 2 + 0] = l0 - lse;
                out[(size_t)gr * 2 + 1] = l1 - lse;
            }
        }
    }
}

extern "C" void kernel_launch(void* const* d_in, const int* in_sizes, int n_in,
                              void* d_out, int out_size, void* d_ws, size_t ws_size,
                              hipStream_t stream) {
    const float* x    = (const float*)d_in[0];
    const int*   ei   = (const int*)d_in[1];
    const float* Win  = (const float*)d_in[2];
    const float* bin  = (const float*)d_in[3];
    const float* W1   = (const float*)d_in[4];
    const float* W2   = (const float*)d_in[5];
    const float* Wout = (const float*)d_in[6];
    const float* bout = (const float*)d_in[7];
    float* out = (float*)d_out;

    const int N = in_sizes[0] / 17;
    const int E = in_sizes[1] / 2;
    const int* rowp = ei;
    const int* colp = ei + E;
    const int span = (N + 63) / 64;   // <= 1600 assumed

    char* p = (char*)d_ws;
    auto alloc = [&](size_t bytes) -> char* {
        char* r = p;
        p += (bytes + 255) & ~(size_t)255;
        return r;
    };
    int*      offs   = (int*)alloc((size_t)(N + 1) * sizeof(int));
    float*    dinv   = (float*)alloc((size_t)N * sizeof(float));
    int*      rc_gc  = (int*)alloc(128 * sizeof(int));
    int*      roffs  = (int*)alloc(65 * sizeof(int));
    int*      srcarr = (int*)alloc((size_t)E * sizeof(int));
    unsigned short* wfold = (unsigned short*)alloc(4 * 8192 * sizeof(unsigned short));
    size_t gbytes  = (size_t)N * 64 * sizeof(unsigned short);
    size_t stbytes = (size_t)E * sizeof(unsigned);
    char*  stg    = alloc(stbytes > gbytes ? stbytes : gbytes);  // staged, later gB
    unsigned short* h0b = (unsigned short*)alloc(gbytes);
    unsigned short* gA  = (unsigned short*)alloc(gbytes);
    unsigned*       staged = (unsigned*)stg;
    unsigned short* gB     = (unsigned short*)stg;  // staged dead after binB

    int* rangecount = rc_gc;
    int* gcur       = rc_gc + 64;
    hipMemsetAsync(rc_gc, 0, 128 * sizeof(int), stream);

    const int TB = 256;
    const int nbA = (E + EPB - 1) / EPB;

    k_rhist<<<nbA, TB, 0, stream>>>(colp, E, span, rangecount);
    k_rscan<<<1, 64, 0, stream>>>(rangecount, roffs, E);
    k_binA<<<nbA, TB, 0, stream>>>(rowp, colp, roffs, gcur, staged, E, span);
    k_binB<<<64, TB, 0, stream>>>(staged, roffs, offs, dinv, srcarr, N, span);

    k_in<<<2048, TB, 0, stream>>>(x, Win, bin, dinv, h0b, gA, N);
    for (int l = 0; l < 4; ++l) {
        float beta = logf(0.5f / (float)(l + 1) + 1.0f);
        float c2 = (1.0f - beta) * ALPHA_C;
        k_wfold<<<32, TB, 0, stream>>>(W1 + (size_t)l * 4096, W2 + (size_t)l * 4096,
                                       beta, c2, wfold + (size_t)l * 8192);
    }

    const int ntiles = (N + 15) >> 4;
    const int nbG = (ntiles + 3) / 4;   // one tile per wave

    // ping-pong g: L0 gA->gB, L1 gB->gA, L2 gA->gB, L3 gB->out (fused head)
    for (int l = 0; l < 4; ++l) {
        float beta = logf(0.5f / (float)(l + 1) + 1.0f);
        float c1 = (1.0f - beta) * (1.0f - ALPHA_C);
        const unsigned short* gin  = (l & 1) ? gB : gA;
        unsigned short*       gout = (l & 1) ? gA : gB;
        if (l < 3)
            k_gmix<0><<<nbG, TB, 0, stream>>>((const uint2*)gin, h0b,
                                              wfold + (size_t)l * 8192,
                                              dinv, offs, srcarr, c1,
                                              nullptr, nullptr, nullptr, gout,
                                              N, ntiles);
        else
            k_gmix<1><<<nbG, TB, 0, stream>>>((const uint2*)gin, h0b,
                                              wfold + (size_t)l * 8192,
                                              dinv, offs, srcarr, c1,
                                              Wout, bout, out, nullptr,
                                              N, ntiles);
    }
}

// Round 12
// 389.021 us; speedup vs baseline: 6.8924x; 1.1452x over previous
//
#include <hip/hip_runtime.h>
#include <math.h>

#define ALPHA_C 0.1f
#define EPB 4096   // edges per block in binA (16 per thread)
#define NR 256     // destination ranges
#define RCAP 8192  // staged capacity per range (mean 6250, +10 sigma < 8192)

typedef __attribute__((ext_vector_type(4))) float f32x4;
typedef __attribute__((ext_vector_type(8))) short bf16x8;

__device__ __forceinline__ float readlane_f(float v, int l) {
    return __int_as_float(__builtin_amdgcn_readlane(__float_as_int(v), l));
}

__device__ __forceinline__ unsigned short bf16_rtne(float f) {
    unsigned u = __float_as_uint(f);
    unsigned r = (u + 0x7FFFu + ((u >> 16) & 1u)) >> 16;
    return (unsigned short)r;
}

__device__ __forceinline__ float bflo(unsigned v) { return __uint_as_float(v << 16); }
__device__ __forceinline__ float bfhi(unsigned v) { return __uint_as_float(v & 0xFFFF0000u); }

// ---- phase A: bin edges into NR destination ranges (fixed-capacity bins) ----
// staged[r*RCAP + k] = (src << 9) | (dst - r*span)   [src < 2^17, local < 512]
__global__ void k_binA(const int* __restrict__ row, const int* __restrict__ col,
                       int* __restrict__ gcur, unsigned* __restrict__ staged,
                       int E, int span) {
    __shared__ int lrun[NR];
    int tid = threadIdx.x;
    int base = blockIdx.x * EPB;
    lrun[tid] = 0;
    __syncthreads();
#pragma unroll
    for (int it = 0; it < 16; ++it) {
        int e = base + it * 256 + tid;
        if (e < E) atomicAdd(&lrun[(unsigned)col[e] / (unsigned)span], 1);
    }
    __syncthreads();
    {
        int cnt = lrun[tid];
        int gb = cnt ? atomicAdd(&gcur[tid], cnt) : 0;
        lrun[tid] = tid * RCAP + gb;   // absolute staged cursor for this block+range
    }
    __syncthreads();
#pragma unroll
    for (int it = 0; it < 16; ++it) {
        int e = base + it * 256 + tid;
        if (e < E) {
            int c = col[e];
            int r = (unsigned)c / (unsigned)span;
            int pos = atomicAdd(&lrun[r], 1);
            staged[pos] = ((unsigned)row[e] << 9) | (unsigned)(c - r * span);
        }
    }
}

// ---- scan the per-range edge counts -> global CSR bases ----
__global__ void k_escan(const int* __restrict__ gcur, int* __restrict__ rangeoffs, int E) {
    __shared__ int s[NR];
    int tid = threadIdx.x;  // one NR-thread block
    int v = gcur[tid];
    s[tid] = v;
    __syncthreads();
    for (int d = 1; d < NR; d <<= 1) {
        int t = (tid >= d) ? s[tid - d] : 0;
        __syncthreads();
        s[tid] += t;
        __syncthreads();
    }
    rangeoffs[tid] = s[tid] - v;
    if (tid == NR - 1) rangeoffs[NR] = E;
}

// ---- phase B: per range: LDS hist -> scan -> offs/dinv -> compact srcarr ----
__global__ void k_binB(const unsigned* __restrict__ staged, const int* __restrict__ gcur,
                       const int* __restrict__ rangeoffs,
                       int* __restrict__ offs, float* __restrict__ dinv,
                       int* __restrict__ srcarr, int N, int span) {
    __shared__ int lcnt[512];
    __shared__ int partial[256];
    int r = blockIdx.x;
    int tid = threadIdx.x;
    int nstart = r * span;
    if (nstart >= N) { if (tid == 0 && r == NR - 1) offs[N] = rangeoffs[NR]; return; }
    int nend = nstart + span; if (nend > N) nend = N;
    int cnt = nend - nstart;
    int estart = rangeoffs[r];
    int ecnt = gcur[r];
    const unsigned* st = staged + (size_t)r * RCAP;
    for (int t = tid; t < cnt; t += 256) lcnt[t] = 0;
    __syncthreads();
    for (int e = tid; e < ecnt; e += 256)
        atomicAdd(&lcnt[st[e] & 0x1FFu], 1);
    __syncthreads();
    // exclusive scan of lcnt[0..cnt) (chunk = 2)
    int chunk = (cnt + 255) / 256;
    int c0 = tid * chunk; if (c0 > cnt) c0 = cnt;
    int c1 = c0 + chunk;  if (c1 > cnt) c1 = cnt;
    int sum = 0;
    for (int t = c0; t < c1; ++t) sum += lcnt[t];
    partial[tid] = sum;
    __syncthreads();
    for (int d = 1; d < 256; d <<= 1) {
        int t = (tid >= d) ? partial[tid - d] : 0;
        __syncthreads();
        partial[tid] += t;
        __syncthreads();
    }
    int run = estart + partial[tid] - sum;
    for (int t = c0; t < c1; ++t) {
        int c = lcnt[t];
        lcnt[t] = run;
        offs[nstart + t] = run;
        dinv[nstart + t] = rsqrtf(1.0f + (float)c);
        run += c;
    }
    if (nend == N && tid == 0) offs[N] = rangeoffs[NR];
    __syncthreads();
    for (int e = tid; e < ecnt; e += 256) {
        unsigned m = st[e];
        int idx = atomicAdd(&lcnt[m & 0x1FFu], 1);
        srcarr[idx] = (int)(m >> 9);
    }
}

// ---- fold weights, all 4 layers: wf[l][n][k] ----
__global__ void k_wfold(const float* __restrict__ W1, const float* __restrict__ W2,
                        unsigned short* __restrict__ wf) {
    int idx = blockIdx.x * 256 + threadIdx.x;
    if (idx < 4 * 8192) {
        int l = idx >> 13;
        int n = (idx >> 7) & 63, k = idx & 127;
        float beta = logf(0.5f / (float)(l + 1) + 1.0f);
        float c2 = (1.0f - beta) * ALPHA_C;
        const float* Wl1 = W1 + (size_t)l * 4096;
        const float* Wl2 = W2 + (size_t)l * 4096;
        float w = (k < 64) ? beta * Wl1[k * 64 + n]
                           : beta * Wl2[(k - 64) * 64 + n] + (((k - 64) == n) ? c2 : 0.0f);
        wf[idx] = bf16_rtne(w);
    }
}

// -- input: h0b = bf16(relu(x @ W_in + b_in));  g = bf16(dinv * relu(...)) --
__global__ void k_in(const float* __restrict__ x, const float* __restrict__ Win,
                     const float* __restrict__ bin, const float* __restrict__ dinv,
                     unsigned short* __restrict__ h0b, unsigned short* __restrict__ g,
                     int N) {
    int lane = threadIdx.x & 63;
    int wave = (blockIdx.x * blockDim.x + threadIdx.x) >> 6;
    int nwaves = (gridDim.x * blockDim.x) >> 6;
    float wreg[17];
#pragma unroll
    for (int k = 0; k < 17; ++k) wreg[k] = Win[k * 64 + lane];
    float breg = bin[lane];
    for (int i = wave; i < N; i += nwaves) {
        float xv = (lane < 17) ? x[i * 17 + lane] : 0.0f;
        float acc = breg;
#pragma unroll
        for (int k = 0; k < 17; ++k) acc += readlane_f(xv, k) * wreg[k];
        float r = fmaxf(acc, 0.0f);
        h0b[(size_t)i * 64 + lane] = bf16_rtne(r);
        g[(size_t)i * 64 + lane] = bf16_rtne(dinv[i] * r);
    }
}

// ---- fused gather+mix (unchanged from R11) ----
template <int MODE>
__global__ void k_gmix(const uint2* __restrict__ gp2,
                       const unsigned short* __restrict__ h0b,
                       const unsigned short* __restrict__ wf,
                       const float* __restrict__ dinv, const int* __restrict__ offs,
                       const int* __restrict__ srcarr, float c1,
                       const float* __restrict__ Wout, const float* __restrict__ bout,
                       float* __restrict__ out, unsigned short* __restrict__ og16,
                       int N, int ntiles) {
    __shared__ float atile_s[4][16][68];
    int lane = threadIdx.x & 63;
    int wv = threadIdx.x >> 6;
    float (*atile)[68] = atile_s[wv];      // wave-private
    int r = lane & 15, q = lane >> 4;      // feature-quad, edge-group
    int t = (blockIdx.x * blockDim.x + threadIdx.x) >> 6;  // one tile per wave
    if (t >= ntiles) return;

    int rl = lane & 15;
    int koff = (lane >> 4) * 8;
    bf16x8 bfrag[4][4];
#pragma unroll
    for (int c = 0; c < 4; ++c)
#pragma unroll
        for (int ks = 0; ks < 4; ++ks)
            bfrag[c][ks] = *(const bf16x8*)&wf[(c * 16 + rl) * 128 + ks * 32 + koff];

    // ---- gather 16 node rows into LDS tile ----
    for (int ii = 0; ii < 16; ++ii) {
        int i = t * 16 + ii; if (i >= N) i = N - 1;
        int e0 = offs[i], e1 = offs[i + 1];
        float a0 = 0.0f, a1 = 0.0f, a2 = 0.0f, a3 = 0.0f;
        for (int base = e0; base < e1; base += 32) {   // 32 edges, 8 per group
            int idx[8];
            uint2 v[8];
#pragma unroll
            for (int u = 0; u < 8; ++u) {
                int eo = base + u * 4 + q;
                idx[u] = srcarr[eo < e1 ? eo : e1 - 1];
            }
#pragma unroll
            for (int u = 0; u < 8; ++u) v[u] = gp2[(size_t)idx[u] * 16 + r];
#pragma unroll
            for (int u = 0; u < 8; ++u) {
                bool ok = (base + u * 4 + q) < e1;
                a0 += ok ? bflo(v[u].x) : 0.0f;
                a1 += ok ? bfhi(v[u].x) : 0.0f;
                a2 += ok ? bflo(v[u].y) : 0.0f;
                a3 += ok ? bfhi(v[u].y) : 0.0f;
            }
        }
        a0 += __shfl_xor(a0, 16, 64); a0 += __shfl_xor(a0, 32, 64);
        a1 += __shfl_xor(a1, 16, 64); a1 += __shfl_xor(a1, 32, 64);
        a2 += __shfl_xor(a2, 16, 64); a2 += __shfl_xor(a2, 32, 64);
        a3 += __shfl_xor(a3, 16, 64); a3 += __shfl_xor(a3, 32, 64);
        if (q == 0) {
            uint2 sv = gp2[(size_t)i * 16 + r];  // self-loop term
            float di = dinv[i];
            f32x4 w = {di * (a0 + bflo(sv.x)), di * (a1 + bfhi(sv.x)),
                       di * (a2 + bflo(sv.y)), di * (a3 + bfhi(sv.y))};
            *(f32x4*)&atile[ii][4 * r] = w;
            if (r == 0) atile[ii][66] = di;
        }
    }

    // ---- MFMA: [A(LDS f32) | h0b(bf16)] @ bfrag ----
    int grow = t * 16 + rl; if (grow >= N) grow = N - 1;
    f32x4 acc[4];
#pragma unroll
    for (int c = 0; c < 4; ++c) acc[c] = (f32x4){0.f, 0.f, 0.f, 0.f};
#pragma unroll
    for (int ks = 0; ks < 4; ++ks) {
        bf16x8 af;
        if (ks < 2) {
            const float* sp = &atile[rl][ks * 32 + koff];
            f32x4 lo = *(const f32x4*)sp;
            f32x4 hi = *(const f32x4*)(sp + 4);
#pragma unroll
            for (int j = 0; j < 4; ++j) af[j] = (short)bf16_rtne(lo[j]);
#pragma unroll
            for (int j = 0; j < 4; ++j) af[4 + j] = (short)bf16_rtne(hi[j]);
        } else {
            af = *(const bf16x8*)&h0b[(size_t)grow * 64 + (ks - 2) * 32 + koff];
        }
#pragma unroll
        for (int c = 0; c < 4; ++c)
            acc[c] = __builtin_amdgcn_mfma_f32_16x16x32_bf16(af, bfrag[c][ks], acc[c], 0, 0, 0);
    }

    if (MODE == 0) {
#pragma unroll
        for (int c = 0; c < 4; ++c) {
            int col = c * 16 + rl;
#pragma unroll
            for (int qq = 0; qq < 4; ++qq) {
                int row16 = (lane >> 4) * 4 + qq;
                int gr = t * 16 + row16;
                if (gr < N) {
                    float v = c1 * atile[row16][col] + acc[c][qq];
                    float rr = fmaxf(v, 0.0f);
                    og16[(size_t)gr * 64 + col] = bf16_rtne(atile[row16][66] * rr);
                }
            }
        }
    } else {
        // ---- fused head: out = log_softmax(h @ Wout + bout) ----
        float w0c[4], w1c[4];
#pragma unroll
        for (int c = 0; c < 4; ++c) {
            int col = c * 16 + rl;
            w0c[c] = Wout[col * 2 + 0];
            w1c[c] = Wout[col * 2 + 1];
        }
        float b0 = bout[0], b1 = bout[1];
        float hq[4][4];
#pragma unroll
        for (int c = 0; c < 4; ++c) {
            int col = c * 16 + rl;
#pragma unroll
            for (int qq = 0; qq < 4; ++qq) {
                int row16 = (lane >> 4) * 4 + qq;
                hq[c][qq] = fmaxf(c1 * atile[row16][col] + acc[c][qq], 0.0f);
            }
        }
#pragma unroll
        for (int qq = 0; qq < 4; ++qq) {
            float p0 = hq[0][qq] * w0c[0] + hq[1][qq] * w0c[1]
                     + hq[2][qq] * w0c[2] + hq[3][qq] * w0c[3];
            float p1 = hq[0][qq] * w1c[0] + hq[1][qq] * w1c[1]
                     + hq[2][qq] * w1c[2] + hq[3][qq] * w1c[3];
#pragma unroll
            for (int d = 1; d < 16; d <<= 1) {
                p0 += __shfl_xor(p0, d, 64);
                p1 += __shfl_xor(p1, d, 64);
            }
            int row16 = (lane >> 4) * 4 + qq;
            int gr = t * 16 + row16;
            if (rl == 0 && gr < N) {
                float l0 = p0 + b0, l1 = p1 + b1;
                float m = fmaxf(l0, l1);
                float lse = m + logf(expf(l0 - m) + expf(l1 - m));
                out[(size_t)gr * 2 + 0] = l0 - lse;
                out[(size_t)gr * 2 + 1] = l1 - lse;
            }
        }
    }
}

extern "C" void kernel_launch(void* const* d_in, const int* in_sizes, int n_in,
                              void* d_out, int out_size, void* d_ws, size_t ws_size,
                              hipStream_t stream) {
    const float* x    = (const float*)d_in[0];
    const int*   ei   = (const int*)d_in[1];
    const float* Win  = (const float*)d_in[2];
    const float* bin  = (const float*)d_in[3];
    const float* W1   = (const float*)d_in[4];
    const float* W2   = (const float*)d_in[5];
    const float* Wout = (const float*)d_in[6];
    const float* bout = (const float*)d_in[7];
    float* out = (float*)d_out;

    const int N = in_sizes[0] / 17;
    const int E = in_sizes[1] / 2;
    const int* rowp = ei;
    const int* colp = ei + E;
    const int span = (N + NR - 1) / NR;   // <= 512 assumed (N <= 131072)

    char* p = (char*)d_ws;
    auto alloc = [&](size_t bytes) -> char* {
        char* r = p;
        p += (bytes + 255) & ~(size_t)255;
        return r;
    };
    int*      offs      = (int*)alloc((size_t)(N + 1) * sizeof(int));
    float*    dinv      = (float*)alloc((size_t)N * sizeof(float));
    int*      gcur      = (int*)alloc(NR * sizeof(int));
    int*      rangeoffs = (int*)alloc((NR + 1) * sizeof(int));
    int*      srcarr    = (int*)alloc((size_t)E * sizeof(int));
    unsigned short* wfold = (unsigned short*)alloc(4 * 8192 * sizeof(unsigned short));
    unsigned* staged    = (unsigned*)alloc((size_t)NR * RCAP * sizeof(unsigned));
    size_t gbytes = (size_t)N * 64 * sizeof(unsigned short);
    unsigned short* h0b = (unsigned short*)alloc(gbytes);
    unsigned short* gA  = (unsigned short*)alloc(gbytes);
    unsigned short* gB  = (unsigned short*)alloc(gbytes);

    hipMemsetAsync(gcur, 0, NR * sizeof(int), stream);

    const int TB = 256;
    const int nbA = (E + EPB - 1) / EPB;

    k_binA<<<nbA, TB, 0, stream>>>(rowp, colp, gcur, staged, E, span);
    k_escan<<<1, NR, 0, stream>>>(gcur, rangeoffs, E);
    k_binB<<<NR, TB, 0, stream>>>(staged, gcur, rangeoffs, offs, dinv, srcarr, N, span);

    k_wfold<<<128, TB, 0, stream>>>(W1, W2, wfold);
    k_in<<<2048, TB, 0, stream>>>(x, Win, bin, dinv, h0b, gA, N);

    const int ntiles = (N + 15) >> 4;
    const int nbG = (ntiles + 3) / 4;   // one tile per wave

    // ping-pong g: L0 gA->gB, L1 gB->gA, L2 gA->gB, L3 gB->out (fused head)
    for (int l = 0; l < 4; ++l) {
        float beta = logf(0.5f / (float)(l + 1) + 1.0f);
        float c1 = (1.0f - beta) * (1.0f - ALPHA_C);
        const unsigned short* gin  = (l & 1) ? gB : gA;
        unsigned short*       gout = (l & 1) ? gA : gB;
        if (l < 3)
            k_gmix<0><<<nbG, TB, 0, stream>>>((const uint2*)gin, h0b,
                                              wfold + (size_t)l * 8192,
                                              dinv, offs, srcarr, c1,
                                              nullptr, nullptr, nullptr, gout,
                                              N, ntiles);
        else
            k_gmix<1><<<nbG, TB, 0, stream>>>((const uint2*)gin, h0b,
                                              wfold + (size_t)l * 8192,
                                              dinv, offs, srcarr, c1,
                                              Wout, bout, out, nullptr,
                                              N, ntiles);
    }
}